// Round 5
// baseline (529.358 us; speedup 1.0000x reference)
//
#include <hip/hip_runtime.h>
#include <hip/hip_bf16.h>

#define T_SEQ 2048
#define DMODEL 1024
#define NHEAD 16
#define DHEAD 64
#define NBATCH 2
#define NROWS (NBATCH * T_SEQ)   // 4096
#define DFFN (4 * DMODEL)        // 4096
#define S1 3072                  // fused [Qc|Kc|V] row stride
#define S2 2048                  // fused [Qs|Ks] row stride
// softmax scale folded into Q projection: (1/sqrt(64)) * log2(e)
#define QSCALE 0.18033688011112042f

typedef __bf16 bf16;
typedef __bf16 bf16x8 __attribute__((ext_vector_type(8)));
typedef __bf16 bf16x4 __attribute__((ext_vector_type(4)));
typedef float f32x4 __attribute__((ext_vector_type(4)));

__device__ __forceinline__ void gload_lds16(const void* g, void* l) {
    __builtin_amdgcn_global_load_lds((const __attribute__((address_space(1))) unsigned int*)g,
                                     (__attribute__((address_space(3))) unsigned int*)l, 16, 0, 0);
}

// ---------------------------------------------------------------- fused 6x [1024][1024] f32 -> bf16 transpose
struct TP6 { const float* src[6]; bf16* dst[6]; };
__global__ void transpose6(TP6 p) {
    __shared__ float tile[32][33];
    const float* in = p.src[blockIdx.z];
    bf16* out = p.dst[blockIdx.z];
    int k0 = blockIdx.y * 32, n0 = blockIdx.x * 32;
    int tx = threadIdx.x & 31, ty = threadIdx.x >> 5;
#pragma unroll
    for (int i = 0; i < 32; i += 8)
        tile[ty + i][tx] = in[(size_t)(k0 + ty + i) * 1024 + n0 + tx];
    __syncthreads();
#pragma unroll
    for (int i = 0; i < 32; i += 8)
        out[(size_t)(n0 + ty + i) * 1024 + k0 + tx] = (bf16)tile[tx][ty + i];
}

__global__ void transpose_f32_to_bf16(const float* __restrict__ in, bf16* __restrict__ out,
                                      int K, int N) {
    __shared__ float tile[32][33];
    int k0 = blockIdx.y * 32, n0 = blockIdx.x * 32;
    int tx = threadIdx.x & 31, ty = threadIdx.x >> 5;
#pragma unroll
    for (int i = 0; i < 32; i += 8)
        tile[ty + i][tx] = in[(size_t)(k0 + ty + i) * N + n0 + tx];
    __syncthreads();
#pragma unroll
    for (int i = 0; i < 32; i += 8)
        out[(size_t)(n0 + ty + i) * K + k0 + tx] = (bf16)tile[tx][ty + i];
}

__global__ void cast_f32_bf16(const float* __restrict__ in, bf16* __restrict__ out, int n4) {
    int i = blockIdx.x * blockDim.x + threadIdx.x;
    if (i >= n4) return;
    float4 v = reinterpret_cast<const float4*>(in)[i];
    bf16x4 o;
    o[0] = (bf16)v.x; o[1] = (bf16)v.y; o[2] = (bf16)v.z; o[3] = (bf16)v.w;
    reinterpret_cast<bf16x4*>(out)[i] = o;
}

__global__ void concat_bias3(const float* __restrict__ b0, const float* __restrict__ b1,
                             const float* __restrict__ b2, float* __restrict__ out, int n) {
    int i = blockIdx.x * 256 + threadIdx.x;
    if (i >= n) return;
    const float* src = (i < 1024) ? b0 : (i < 2048) ? b1 : b2;
    out[i] = src[i & 1023];
}

// ---------------------------------------------------------------- LayerNorm row (D=1024), out bf16
__global__ void layernorm_bf16(const float* __restrict__ x, const float* __restrict__ w,
                               const float* __restrict__ b, bf16* __restrict__ out) {
    int row = blockIdx.x;
    int t = threadIdx.x;
    const float* xr = x + (size_t)row * DMODEL;
    float4 v = reinterpret_cast<const float4*>(xr)[t];
    float s = v.x + v.y + v.z + v.w;
    float sq = v.x * v.x + v.y * v.y + v.z * v.z + v.w * v.w;
#pragma unroll
    for (int off = 1; off < 64; off <<= 1) {
        s += __shfl_xor(s, off);
        sq += __shfl_xor(sq, off);
    }
    __shared__ float ss[4], ssq[4];
    int wid = t >> 6;
    if ((t & 63) == 0) { ss[wid] = s; ssq[wid] = sq; }
    __syncthreads();
    s = ss[0] + ss[1] + ss[2] + ss[3];
    sq = ssq[0] + ssq[1] + ssq[2] + ssq[3];
    float mu = s * (1.0f / DMODEL);
    float var = sq * (1.0f / DMODEL) - mu * mu;
    float rstd = rsqrtf(var + 1e-5f);
    float4 wv = reinterpret_cast<const float4*>(w)[t];
    float4 bv = reinterpret_cast<const float4*>(b)[t];
    bf16x4 o;
    o[0] = (bf16)((v.x - mu) * rstd * wv.x + bv.x);
    o[1] = (bf16)((v.y - mu) * rstd * wv.y + bv.y);
    o[2] = (bf16)((v.z - mu) * rstd * wv.z + bv.z);
    o[3] = (bf16)((v.w - mu) * rstd * wv.w + bv.w);
    reinterpret_cast<bf16x4*>(out + (size_t)row * DMODEL)[t] = o;
}

// ---------------------------------------------------------------- GEMM (m97 structure + XCD swizzle)
// MODE 0: bf16 out  MODE 1: bf16 out + exact GELU  MODE 2: f32 out = v + bias + res
// SCALEQ: multiply cols < 1024 by QSCALE (softmax scale folded into Q projections)
template <int BN, int MODE, int SCALEQ>
__global__ __launch_bounds__(256, 3) void gemm_glds(const bf16* __restrict__ A,
                                                    const bf16* __restrict__ Bt,
                                                    const float* __restrict__ bias,
                                                    const float* __restrict__ res,
                                                    void* __restrict__ Cout,
                                                    int M, int N, int K) {
    constexpr int BM = 128, BK = 32;
    constexpr int WN = BN / 2;        // per-wave cols (2x2 wave grid)
    constexpr int NB = BN / 64;       // B staging chunks per wave
    constexpr int NI = WN / 16;       // acc cols
    __shared__ __align__(16) bf16 As[BM * BK];
    __shared__ __align__(16) bf16 Bs[BN * BK];
    // bijective XCD swizzle (all our grids are %8==0): contiguous tile chunk per XCD
    int lin = blockIdx.y * gridDim.x + blockIdx.x;
    int cpx = (gridDim.x * gridDim.y) >> 3;
    int swz = (lin & 7) * cpx + (lin >> 3);
    int bx = swz % gridDim.x, by = swz / gridDim.x;
    int m0 = by * BM, n0 = bx * BN;
    int t = threadIdx.x, lane = t & 63, w = t >> 6;
    int wr = w >> 1, wc = w & 1;
    int l15 = lane & 15, lg = lane >> 4;
    int lr = lane >> 2, lc = (lane & 3) << 3;   // staging: 16 rows/chunk, 4 x 8-elem per row
    f32x4 acc[4][NI] = {};

    const bf16* Ab = A + (size_t)(m0 + lr) * K + lc;
    const bf16* Bb = Bt + (size_t)(n0 + lr) * K + lc;

    for (int kb = 0; kb < K; kb += BK) {
        __syncthreads();
#pragma unroll
        for (int i = 0; i < 2; i++) {
            int c = w * 2 + i;
            gload_lds16(Ab + (size_t)(c * 16) * K + kb, &As[c * 512]);
        }
#pragma unroll
        for (int i = 0; i < NB; i++) {
            int c = w * NB + i;
            gload_lds16(Bb + (size_t)(c * 16) * K + kb, &Bs[c * 512]);
        }
        __syncthreads();
        bf16x8 af[4], bfr[NI];
#pragma unroll
        for (int i = 0; i < 4; i++)
            af[i] = *(const bf16x8*)&As[(wr * 64 + i * 16 + l15) * BK + lg * 8];
#pragma unroll
        for (int i = 0; i < NI; i++)
            bfr[i] = *(const bf16x8*)&Bs[(wc * WN + i * 16 + l15) * BK + lg * 8];
#pragma unroll
        for (int mi = 0; mi < 4; mi++)
#pragma unroll
            for (int ni = 0; ni < NI; ni++)
                acc[mi][ni] = __builtin_amdgcn_mfma_f32_16x16x32_bf16(af[mi], bfr[ni], acc[mi][ni], 0, 0, 0);
    }

#pragma unroll
    for (int mi = 0; mi < 4; mi++) {
#pragma unroll
        for (int ni = 0; ni < NI; ni++) {
            int col = n0 + wc * WN + ni * 16 + l15;
            float bsv = bias[col];
#pragma unroll
            for (int r = 0; r < 4; r++) {
                int row = m0 + wr * 64 + mi * 16 + lg * 4 + r;
                float v = acc[mi][ni][r] + bsv;
                if (SCALEQ && col < 1024) v *= QSCALE;
                size_t idx = (size_t)row * N + col;
                if (MODE == 0) {
                    ((bf16*)Cout)[idx] = (bf16)v;
                } else if (MODE == 1) {
                    float g = 0.5f * v * (1.0f + erff(v * 0.70710678118654752f));
                    ((bf16*)Cout)[idx] = (bf16)g;
                } else {
                    ((float*)Cout)[idx] = v + res[idx];
                }
            }
        }
    }
}

// ---------------------------------------------------------------- flash attention, dual-QK (qk 128), causal
// grid (T/32, B*H), 256 threads = 4 waves: wave w -> qsub = w&1 (16 q-rows), kpar = w>>1
// (k-split: wave kpar handles subtile kpar of each staged 64-k tile). Partial (m,l,acc)
// merged across kpar pairs via LDS at the end. Q prescaled by QSCALE -> exp2 softmax.
__global__ __launch_bounds__(256, 4) void flash_attn(const bf16* __restrict__ QKV,
                                                     const bf16* __restrict__ QsKs,
                                                     bf16* __restrict__ O) {
    __shared__ __align__(16) bf16 Klds[64 * 128];   // XOR-swizzled: idx ^= (row&7)<<3
    __shared__ __align__(16) bf16 Vt[64][72];       // [d][k], rotated conflict-free writes
    __shared__ __align__(16) bf16 Plds[4][16][36];  // per-wave P tile [q][k32]

    int bh = blockIdx.y;
    int b = bh >> 4, h = bh & 15;
    int q0 = (gridDim.x - 1 - blockIdx.x) * 32;  // longest blocks first
    int t = threadIdx.x;
    int w = t >> 6, lane = t & 63;
    int qsub = w & 1, kpar = w >> 1;
    int l15 = lane & 15, lg = lane >> 4;
    int qw = q0 + qsub * 16;
    int qg = qw + l15;          // this lane's q row (softmax stats column)

    // Q' fragments (qk-dim 128 = 4 chunks of 32) in registers; prescaled by QSCALE in GEMM
    size_t qrow = (size_t)(b * T_SEQ + qg);
    const bf16* qcp = QKV + qrow * S1 + h * DHEAD;
    const bf16* qsp = QsKs + qrow * S2 + h * DHEAD;
    bf16x8 qf[4];
#pragma unroll
    for (int c = 0; c < 2; c++) {
        qf[c]     = *(const bf16x8*)(qcp + c * 32 + lg * 8);
        qf[2 + c] = *(const bf16x8*)(qsp + c * 32 + lg * 8);
    }

    float m_run = -1e30f, l_part = 0.0f;
    f32x4 acc[4] = {};

    // staging maps
    int krow = t >> 4;                 // 0..15
    int kdd = (t & 15) << 3;           // 0..120
    int vr = t >> 3, j0 = t & 7;       // V: row base, rotation

    const bf16* kcb = QKV + (size_t)(b * T_SEQ) * S1 + 1024 + h * DHEAD;
    const bf16* ksb = QsKs + (size_t)(b * T_SEQ) * S2 + 1024 + h * DHEAD;
    const bf16* vb  = QKV + (size_t)(b * T_SEQ) * S1 + 2048 + h * DHEAD + j0 * 8;
    const bf16* ksrc = (kdd < 64) ? (kcb + kdd) : (ksb + kdd - 64);
    size_t kstride = (kdd < 64) ? S1 : S2;

    int nt = (q0 + 95) >> 6;   // 64-k tiles needed to cover k <= q0+31
    bf16x8 kreg[4], vreg[2];
#pragma unroll
    for (int i = 0; i < 4; i++) kreg[i] = *(const bf16x8*)(ksrc + (size_t)(i * 16 + krow) * kstride);
#pragma unroll
    for (int i = 0; i < 2; i++) vreg[i] = *(const bf16x8*)(vb + (size_t)(i * 32 + vr) * S1);

    for (int it = 0; it < nt; ++it) {
        __syncthreads();   // previous compute done; LDS free
#pragma unroll
        for (int i = 0; i < 4; i++) {
            int row = i * 16 + krow;
            int idx = ((row << 7) + kdd) ^ ((row & 7) << 3);
            *(bf16x8*)&Klds[idx] = kreg[i];
        }
#pragma unroll
        for (int i = 0; i < 2; i++) {
            int r = i * 32 + vr;
#pragma unroll
            for (int e = 0; e < 8; e++) {
                int j = (e + j0) & 7;
                Vt[j0 * 8 + j][r] = vreg[i][j];
            }
        }
        __syncthreads();
        if (it + 1 < nt) {   // prefetch next tile (latency hides under compute)
            int kn = (it + 1) * 64;
#pragma unroll
            for (int i = 0; i < 4; i++) kreg[i] = *(const bf16x8*)(ksrc + (size_t)(kn + i * 16 + krow) * kstride);
#pragma unroll
            for (int i = 0; i < 2; i++) vreg[i] = *(const bf16x8*)(vb + (size_t)(kn + i * 32 + vr) * S1);
        }

        int kk = it * 64 + kpar * 32;      // this wave's k-subtile
        if (kk <= qw + 15) {
            // QK^T (swapped): lane holds col=q(l15), row=k(lg*4+r)
            f32x4 st[2];
            __builtin_amdgcn_s_setprio(1);
#pragma unroll
            for (int tt = 0; tt < 2; tt++) {
                f32x4 z = {};
#pragma unroll
                for (int c = 0; c < 4; c++) {
                    int row = kpar * 32 + tt * 16 + l15;
                    int idx = ((row << 7) + c * 32 + lg * 8) ^ ((row & 7) << 3);
                    bf16x8 kf = *(const bf16x8*)&Klds[idx];
                    z = __builtin_amdgcn_mfma_f32_16x16x32_bf16(kf, qf[c], z, 0, 0, 0);
                }
                st[tt] = z;
            }
            __builtin_amdgcn_s_setprio(0);
            float s[8], lm = -1e30f;
            if (kk + 31 <= qw) {   // wave-uniform: fully unmasked
#pragma unroll
                for (int tt = 0; tt < 2; tt++)
#pragma unroll
                    for (int r = 0; r < 4; r++) {
                        float sv = st[tt][r];
                        s[tt * 4 + r] = sv;
                        lm = fmaxf(lm, sv);
                    }
            } else {
#pragma unroll
                for (int tt = 0; tt < 2; tt++)
#pragma unroll
                    for (int r = 0; r < 4; r++) {
                        int kgl = kk + tt * 16 + lg * 4 + r;
                        float sv = st[tt][r];
                        if (kgl > qg) sv = -1e30f;
                        s[tt * 4 + r] = sv;
                        lm = fmaxf(lm, sv);
                    }
            }
            // defer-max: full rescale path only when max grew > ~8 nats (11.5 bits)
            if (__any(lm > m_run + 11.5f)) {
                float rm = lm;
                rm = fmaxf(rm, __shfl_xor(rm, 16));
                rm = fmaxf(rm, __shfl_xor(rm, 32));
                float m_new = fmaxf(m_run, rm);
                float sc = exp2f(m_run - m_new);
                l_part *= sc;
#pragma unroll
                for (int r = 0; r < 4; r++) {
                    float oscr = __shfl(sc, lg * 4 + r);
#pragma unroll
                    for (int dt = 0; dt < 4; dt++) acc[dt][r] *= oscr;
                }
                m_run = m_new;
            }
            float p[8];
#pragma unroll
            for (int j = 0; j < 8; j++) { p[j] = exp2f(s[j] - m_run); l_part += p[j]; }
            bf16x4 pk0, pk1;
#pragma unroll
            for (int r = 0; r < 4; r++) { pk0[r] = (bf16)p[r]; pk1[r] = (bf16)p[4 + r]; }
            *(bf16x4*)&Plds[w][l15][lg * 4] = pk0;
            *(bf16x4*)&Plds[w][l15][16 + lg * 4] = pk1;
            asm volatile("s_waitcnt lgkmcnt(0)" ::: "memory");
            __builtin_amdgcn_sched_barrier(0);
            bf16x8 paf = *(const bf16x8*)&Plds[w][l15][lg * 8];
            __builtin_amdgcn_s_setprio(1);
#pragma unroll
            for (int dt = 0; dt < 4; dt++) {
                bf16x8 vf = *(const bf16x8*)&Vt[dt * 16 + l15][kpar * 32 + lg * 8];
                acc[dt] = __builtin_amdgcn_mfma_f32_16x16x32_bf16(paf, vf, acc[dt], 0, 0, 0);
            }
            __builtin_amdgcn_s_setprio(0);
        }
    }

    // ---- merge k-split partials (kpar 1 -> kpar 0) via LDS (alias Klds) ----
    __syncthreads();
    float* mb = (float*)Klds;   // [qsub][lane][18]: 16 acc + m + l  (9216 B < 16384 B)
    if (kpar == 1) {
        int base = (qsub * 64 + lane) * 18;
#pragma unroll
        for (int dt = 0; dt < 4; dt++)
#pragma unroll
            for (int r = 0; r < 4; r++) mb[base + dt * 4 + r] = acc[dt][r];
        mb[base + 16] = m_run;
        mb[base + 17] = l_part;
    }
    __syncthreads();
    if (kpar == 0) {
        int base = (qsub * 64 + lane) * 18;
        float m1 = mb[base + 16], l1 = mb[base + 17];
        float m = fmaxf(m_run, m1);
        float f0 = exp2f(m_run - m), f1 = exp2f(m1 - m);
        float l = l_part * f0 + l1 * f1;
        l += __shfl_xor(l, 16);
        l += __shfl_xor(l, 32);
        float linv = 1.0f / l;   // stats live in q=l15 domain
#pragma unroll
        for (int r = 0; r < 4; r++) {
            float g0 = __shfl(f0, lg * 4 + r);
            float g1 = __shfl(f1, lg * 4 + r);
            float li = __shfl(linv, lg * 4 + r);
            size_t orow = (size_t)(b * T_SEQ + qw + lg * 4 + r);
#pragma unroll
            for (int dt = 0; dt < 4; dt++) {
                float v = acc[dt][r] * g0 + mb[base + dt * 4 + r] * g1;
                O[orow * DMODEL + h * DHEAD + dt * 16 + l15] = (bf16)(v * li);
            }
        }
    }
}

// ---------------------------------------------------------------- launch
extern "C" void kernel_launch(void* const* d_in, const int* in_sizes, int n_in,
                              void* d_out, int out_size, void* d_ws, size_t ws_size,
                              hipStream_t stream) {
    const float* x = (const float*)d_in[0];
    const float* pos = (const float*)d_in[1];
    const float* Wqc = (const float*)d_in[2];  const float* bqc = (const float*)d_in[3];
    const float* Wkc = (const float*)d_in[4];  const float* bkc = (const float*)d_in[5];
    const float* Wqs = (const float*)d_in[6];  const float* bqs = (const float*)d_in[7];
    const float* Wks = (const float*)d_in[8];  const float* bks = (const float*)d_in[9];
    const float* Wv  = (const float*)d_in[10]; const float* bv  = (const float*)d_in[11];
    const float* Wo  = (const float*)d_in[12]; const float* bo  = (const float*)d_in[13];
    const float* ln1w = (const float*)d_in[14]; const float* ln1b = (const float*)d_in[15];
    const float* ln2w = (const float*)d_in[16]; const float* ln2b = (const float*)d_in[17];
    const float* Wf1 = (const float*)d_in[18]; const float* bf1 = (const float*)d_in[19];
    const float* Wf2 = (const float*)d_in[20]; const float* bf2 = (const float*)d_in[21];
    float* out = (float*)d_out;

    char* wsp = (char*)d_ws;
    size_t off = 0;
    auto alloc = [&](size_t bytes) { void* p = wsp + off; off += (bytes + 255) & ~(size_t)255; return p; };
    const size_t DD = (size_t)DMODEL * DMODEL;
    const size_t RD = (size_t)NROWS * DMODEL;
    bf16* Wcat1 = (bf16*)alloc(3 * DD * 2);     // [Qc|Kc|V] transposed
    bf16* Wcat2 = (bf16*)alloc(2 * DD * 2);     // [Qs|Ks] transposed
    bf16* WoT  = (bf16*)alloc(DD * 2);
    bf16* Wf1T = (bf16*)alloc((size_t)DMODEL * DFFN * 2);
    bf16* Wf2T = (bf16*)alloc((size_t)DMODEL * DFFN * 2);
    float* bc1 = (float*)alloc(3 * DMODEL * 4);
    float* bc2 = (float*)alloc(2 * DMODEL * 4);
    bf16* hb   = (bf16*)alloc(RD * 2);
    bf16* posb = (bf16*)alloc(RD * 2);
    bf16* C1   = (bf16*)alloc((size_t)NROWS * S1 * 2);  // [Qc|Kc|V]
    bf16* C2   = (bf16*)alloc((size_t)NROWS * S2 * 2);  // [Qs|Ks]
    bf16* Ab   = (bf16*)alloc(RD * 2);
    float* x2  = (float*)alloc(RD * 4);
    bf16* h2b  = (bf16*)alloc(RD * 2);
    bf16* gb   = (bf16*)alloc((size_t)NROWS * DFFN * 2);

    // 1) weight transposes
    TP6 tp;
    tp.src[0] = Wqc; tp.dst[0] = Wcat1;
    tp.src[1] = Wkc; tp.dst[1] = Wcat1 + DD;
    tp.src[2] = Wv;  tp.dst[2] = Wcat1 + 2 * DD;
    tp.src[3] = Wqs; tp.dst[3] = Wcat2;
    tp.src[4] = Wks; tp.dst[4] = Wcat2 + DD;
    tp.src[5] = Wo;  tp.dst[5] = WoT;
    transpose6<<<dim3(32, 32, 6), 256, 0, stream>>>(tp);
    transpose_f32_to_bf16<<<dim3(DFFN / 32, DMODEL / 32), 256, 0, stream>>>(Wf1, Wf1T, DMODEL, DFFN);
    transpose_f32_to_bf16<<<dim3(DMODEL / 32, DFFN / 32), 256, 0, stream>>>(Wf2, Wf2T, DFFN, DMODEL);
    concat_bias3<<<12, 256, 0, stream>>>(bqc, bkc, bv, bc1, 3 * DMODEL);
    concat_bias3<<<8, 256, 0, stream>>>(bqs, bks, bqs, bc2, 2 * DMODEL);

    // 2) LN1 + pos cast
    layernorm_bf16<<<NROWS, 256, 0, stream>>>(x, ln1w, ln1b, hb);
    cast_f32_bf16<<<(RD / 4 + 255) / 256, 256, 0, stream>>>(pos, posb, RD / 4);

    // 3) fused projections (Q columns prescaled by QSCALE)
    gemm_glds<128, 0, 1><<<dim3(S1 / 128, NROWS / 128), 256, 0, stream>>>(hb, Wcat1, bc1, nullptr, C1, NROWS, S1, DMODEL);
    gemm_glds<128, 0, 1><<<dim3(S2 / 128, NROWS / 128), 256, 0, stream>>>(posb, Wcat2, bc2, nullptr, C2, NROWS, S2, DMODEL);

    // 4) flash attention (split-K, QBLK=32)
    flash_attn<<<dim3(T_SEQ / 32, NBATCH * NHEAD), 256, 0, stream>>>(C1, C2, Ab);

    // 5) Wo + residual -> x2 (f32)
    gemm_glds<64, 2, 0><<<dim3(DMODEL / 64, NROWS / 128), 256, 0, stream>>>(Ab, WoT, bo, x, x2, NROWS, DMODEL, DMODEL);

    // 6) LN2
    layernorm_bf16<<<NROWS, 256, 0, stream>>>(x2, ln2w, ln2b, h2b);

    // 7) FFN1 + GELU
    gemm_glds<128, 1, 0><<<dim3(DFFN / 128, NROWS / 128), 256, 0, stream>>>(h2b, Wf1T, bf1, nullptr, gb, NROWS, DFFN, DMODEL);

    // 8) FFN2 + residual -> out (f32)
    gemm_glds<64, 2, 0><<<dim3(DMODEL / 64, NROWS / 128), 256, 0, stream>>>(gb, Wf2T, bf2, x2, out, NROWS, DMODEL, DFFN);
}

// Round 6
// 485.863 us; speedup vs baseline: 1.0895x; 1.0895x over previous
//
#include <hip/hip_runtime.h>
#include <hip/hip_bf16.h>

#define T_SEQ 2048
#define DMODEL 1024
#define NHEAD 16
#define DHEAD 64
#define NBATCH 2
#define NROWS (NBATCH * T_SEQ)   // 4096
#define DFFN (4 * DMODEL)        // 4096
#define S1 3072                  // fused [Qc|Kc|V] row stride
#define S2 2048                  // fused [Qs|Ks] row stride
// softmax scale folded into Q projection: (1/sqrt(64)) * log2(e)
#define QSCALE 0.18033688011112042f

typedef __bf16 bf16;
typedef __bf16 bf16x8 __attribute__((ext_vector_type(8)));
typedef __bf16 bf16x4 __attribute__((ext_vector_type(4)));
typedef float f32x4 __attribute__((ext_vector_type(4)));

__device__ __forceinline__ void gload_lds16(const void* g, void* l) {
    __builtin_amdgcn_global_load_lds((const __attribute__((address_space(1))) unsigned int*)g,
                                     (__attribute__((address_space(3))) unsigned int*)l, 16, 0, 0);
}

// ---------------------------------------------------------------- fused 6x [1024][1024] f32 -> bf16 transpose
struct TP6 { const float* src[6]; bf16* dst[6]; };
__global__ void transpose6(TP6 p) {
    __shared__ float tile[32][33];
    const float* in = p.src[blockIdx.z];
    bf16* out = p.dst[blockIdx.z];
    int k0 = blockIdx.y * 32, n0 = blockIdx.x * 32;
    int tx = threadIdx.x & 31, ty = threadIdx.x >> 5;
#pragma unroll
    for (int i = 0; i < 32; i += 8)
        tile[ty + i][tx] = in[(size_t)(k0 + ty + i) * 1024 + n0 + tx];
    __syncthreads();
#pragma unroll
    for (int i = 0; i < 32; i += 8)
        out[(size_t)(n0 + ty + i) * 1024 + k0 + tx] = (bf16)tile[tx][ty + i];
}

__global__ void transpose_f32_to_bf16(const float* __restrict__ in, bf16* __restrict__ out,
                                      int K, int N) {
    __shared__ float tile[32][33];
    int k0 = blockIdx.y * 32, n0 = blockIdx.x * 32;
    int tx = threadIdx.x & 31, ty = threadIdx.x >> 5;
#pragma unroll
    for (int i = 0; i < 32; i += 8)
        tile[ty + i][tx] = in[(size_t)(k0 + ty + i) * N + n0 + tx];
    __syncthreads();
#pragma unroll
    for (int i = 0; i < 32; i += 8)
        out[(size_t)(n0 + ty + i) * K + k0 + tx] = (bf16)tile[tx][ty + i];
}

__global__ void cast_f32_bf16(const float* __restrict__ in, bf16* __restrict__ out, int n4) {
    int i = blockIdx.x * blockDim.x + threadIdx.x;
    if (i >= n4) return;
    float4 v = reinterpret_cast<const float4*>(in)[i];
    bf16x4 o;
    o[0] = (bf16)v.x; o[1] = (bf16)v.y; o[2] = (bf16)v.z; o[3] = (bf16)v.w;
    reinterpret_cast<bf16x4*>(out)[i] = o;
}

__global__ void concat_bias3(const float* __restrict__ b0, const float* __restrict__ b1,
                             const float* __restrict__ b2, float* __restrict__ out, int n) {
    int i = blockIdx.x * 256 + threadIdx.x;
    if (i >= n) return;
    const float* src = (i < 1024) ? b0 : (i < 2048) ? b1 : b2;
    out[i] = src[i & 1023];
}

// ---------------------------------------------------------------- LayerNorm row (D=1024), out bf16
__global__ void layernorm_bf16(const float* __restrict__ x, const float* __restrict__ w,
                               const float* __restrict__ b, bf16* __restrict__ out) {
    int row = blockIdx.x;
    int t = threadIdx.x;
    const float* xr = x + (size_t)row * DMODEL;
    float4 v = reinterpret_cast<const float4*>(xr)[t];
    float s = v.x + v.y + v.z + v.w;
    float sq = v.x * v.x + v.y * v.y + v.z * v.z + v.w * v.w;
#pragma unroll
    for (int off = 1; off < 64; off <<= 1) {
        s += __shfl_xor(s, off);
        sq += __shfl_xor(sq, off);
    }
    __shared__ float ss[4], ssq[4];
    int wid = t >> 6;
    if ((t & 63) == 0) { ss[wid] = s; ssq[wid] = sq; }
    __syncthreads();
    s = ss[0] + ss[1] + ss[2] + ss[3];
    sq = ssq[0] + ssq[1] + ssq[2] + ssq[3];
    float mu = s * (1.0f / DMODEL);
    float var = sq * (1.0f / DMODEL) - mu * mu;
    float rstd = rsqrtf(var + 1e-5f);
    float4 wv = reinterpret_cast<const float4*>(w)[t];
    float4 bv = reinterpret_cast<const float4*>(b)[t];
    bf16x4 o;
    o[0] = (bf16)((v.x - mu) * rstd * wv.x + bv.x);
    o[1] = (bf16)((v.y - mu) * rstd * wv.y + bv.y);
    o[2] = (bf16)((v.z - mu) * rstd * wv.z + bv.z);
    o[3] = (bf16)((v.w - mu) * rstd * wv.w + bv.w);
    reinterpret_cast<bf16x4*>(out + (size_t)row * DMODEL)[t] = o;
}

// ---------------------------------------------------------------- GEMM (m97 staging + 2-phase dbuf pipeline + XCD swizzle)
// MODE 0: bf16 out  MODE 1: bf16 out + exact GELU  MODE 2: f32 out = v + bias + res
// SCALEQ: multiply cols < 1024 by QSCALE (softmax scale folded into Q projections)
template <int BN, int MODE, int SCALEQ>
__global__ __launch_bounds__(256, 3) void gemm_glds(const bf16* __restrict__ A,
                                                    const bf16* __restrict__ Bt,
                                                    const float* __restrict__ bias,
                                                    const float* __restrict__ res,
                                                    void* __restrict__ Cout,
                                                    int M, int N, int K) {
    constexpr int BM = 128, BK = 32;
    constexpr int WN = BN / 2;        // per-wave cols (2x2 wave grid)
    constexpr int NB = BN / 64;       // B staging chunks per wave
    constexpr int NI = WN / 16;       // acc cols
    __shared__ __align__(16) bf16 As[2][BM * BK];
    __shared__ __align__(16) bf16 Bs[2][BN * BK];
    // bijective XCD swizzle (all our grids are %8==0): contiguous tile chunk per XCD
    int lin = blockIdx.y * gridDim.x + blockIdx.x;
    int cpx = (gridDim.x * gridDim.y) >> 3;
    int swz = (lin & 7) * cpx + (lin >> 3);
    int bx = swz % gridDim.x, by = swz / gridDim.x;
    int m0 = by * BM, n0 = bx * BN;
    int t = threadIdx.x, lane = t & 63, w = t >> 6;
    int wr = w >> 1, wc = w & 1;
    int l15 = lane & 15, lg = lane >> 4;
    int lr = lane >> 2, lc = (lane & 3) << 3;   // staging: 16 rows/chunk, 4 x 8-elem per row
    f32x4 acc[4][NI] = {};

    const bf16* Ab = A + (size_t)(m0 + lr) * K + lc;
    const bf16* Bb = Bt + (size_t)(n0 + lr) * K + lc;

    auto stage = [&](int buf, int kb) {
#pragma unroll
        for (int i = 0; i < 2; i++) {
            int c = w * 2 + i;
            gload_lds16(Ab + (size_t)(c * 16) * K + kb, &As[buf][c * 512]);
        }
#pragma unroll
        for (int i = 0; i < NB; i++) {
            int c = w * NB + i;
            gload_lds16(Bb + (size_t)(c * 16) * K + kb, &Bs[buf][c * 512]);
        }
    };

    int NT = K / BK;
    stage(0, 0);
    __syncthreads();   // compiler emits vmcnt(0) drain before s_barrier

    for (int kt = 0; kt < NT; ++kt) {
        int cur = kt & 1;
        if (kt + 1 < NT) stage(cur ^ 1, (kt + 1) * BK);   // overlap with compute below
        bf16x8 af[4], bfr[NI];
#pragma unroll
        for (int i = 0; i < 4; i++)
            af[i] = *(const bf16x8*)&As[cur][(wr * 64 + i * 16 + l15) * BK + lg * 8];
#pragma unroll
        for (int i = 0; i < NI; i++)
            bfr[i] = *(const bf16x8*)&Bs[cur][(wc * WN + i * 16 + l15) * BK + lg * 8];
#pragma unroll
        for (int mi = 0; mi < 4; mi++)
#pragma unroll
            for (int ni = 0; ni < NI; ni++)
                acc[mi][ni] = __builtin_amdgcn_mfma_f32_16x16x32_bf16(af[mi], bfr[ni], acc[mi][ni], 0, 0, 0);
        __syncthreads();   // drains next-tile loads + protects buffer reuse
    }

#pragma unroll
    for (int mi = 0; mi < 4; mi++) {
#pragma unroll
        for (int ni = 0; ni < NI; ni++) {
            int col = n0 + wc * WN + ni * 16 + l15;
            float bsv = bias[col];
#pragma unroll
            for (int r = 0; r < 4; r++) {
                int row = m0 + wr * 64 + mi * 16 + lg * 4 + r;
                float v = acc[mi][ni][r] + bsv;
                if (SCALEQ && col < 1024) v *= QSCALE;
                size_t idx = (size_t)row * N + col;
                if (MODE == 0) {
                    ((bf16*)Cout)[idx] = (bf16)v;
                } else if (MODE == 1) {
                    float g = 0.5f * v * (1.0f + erff(v * 0.70710678118654752f));
                    ((bf16*)Cout)[idx] = (bf16)g;
                } else {
                    ((float*)Cout)[idx] = v + res[idx];
                }
            }
        }
    }
}

// ---------------------------------------------------------------- flash attention, dual-QK (qk 128), causal
// grid (16, B*H), 256 threads = 4 waves, wave w owns 16 q-rows. Block j runs q-tiles
// {31-j, j} sequentially -> constant work per block (no drain tail), all blocks co-resident.
// Q prescaled by QSCALE in projection -> exp2 softmax. XOR-swizzled K staging, defer-max.
__global__ __launch_bounds__(256, 4) void flash_attn(const bf16* __restrict__ QKV,
                                                     const bf16* __restrict__ QsKs,
                                                     bf16* __restrict__ O) {
    __shared__ __align__(16) bf16 Klds[64 * 128];   // XOR-swizzled: idx ^= (row&7)<<3
    __shared__ __align__(16) bf16 Vt[64][72];       // [d][k], rotated conflict-free writes
    __shared__ __align__(16) bf16 Plds[4][16][36];  // per-wave P tile [q][k32]

    int bh = blockIdx.y;
    int b = bh >> 4, h = bh & 15;
    int t = threadIdx.x;
    int w = t >> 6, lane = t & 63;
    int l15 = lane & 15, lg = lane >> 4;

    // staging maps
    int krow = t >> 4;                 // 0..15
    int kdd = (t & 15) << 3;           // 0..120
    int vr = t >> 3, j0 = t & 7;       // V: row base, rotation

    const bf16* kcb = QKV + (size_t)(b * T_SEQ) * S1 + 1024 + h * DHEAD;
    const bf16* ksb = QsKs + (size_t)(b * T_SEQ) * S2 + 1024 + h * DHEAD;
    const bf16* vb  = QKV + (size_t)(b * T_SEQ) * S1 + 2048 + h * DHEAD + j0 * 8;
    const bf16* ksrc = (kdd < 64) ? (kcb + kdd) : (ksb + kdd - 64);
    size_t kstride = (kdd < 64) ? S1 : S2;

    // register prefetch pipeline: holds tile 0 at entry of each pass
    bf16x8 kreg[4], vreg[2];
#pragma unroll
    for (int i = 0; i < 4; i++) kreg[i] = *(const bf16x8*)(ksrc + (size_t)(i * 16 + krow) * kstride);
#pragma unroll
    for (int i = 0; i < 2; i++) vreg[i] = *(const bf16x8*)(vb + (size_t)(i * 32 + vr) * S1);

    for (int p = 0; p < 2; ++p) {
        int jj = p ? blockIdx.x : (31 - blockIdx.x);   // heavy tile first
        int q0 = jj * 64;
        int qw = q0 + w * 16;
        int qg = qw + l15;          // this lane's q row (softmax stats column)

        size_t qrow = (size_t)(b * T_SEQ + qg);
        const bf16* qcp = QKV + qrow * S1 + h * DHEAD;
        const bf16* qsp = QsKs + qrow * S2 + h * DHEAD;
        bf16x8 qf[4];
#pragma unroll
        for (int c = 0; c < 2; c++) {
            qf[c]     = *(const bf16x8*)(qcp + c * 32 + lg * 8);
            qf[2 + c] = *(const bf16x8*)(qsp + c * 32 + lg * 8);
        }

        float m_run = -1e30f, l_part = 0.0f;
        f32x4 acc[4] = {};
        int nt = q0 / 64 + 1;

        for (int it = 0; it < nt; ++it) {
            __syncthreads();   // previous compute done; LDS free
#pragma unroll
            for (int i = 0; i < 4; i++) {
                int row = i * 16 + krow;
                int idx = ((row << 7) + kdd) ^ ((row & 7) << 3);
                *(bf16x8*)&Klds[idx] = kreg[i];
            }
#pragma unroll
            for (int i = 0; i < 2; i++) {
                int r = i * 32 + vr;
#pragma unroll
                for (int e = 0; e < 8; e++) {
                    int j = (e + j0) & 7;
                    Vt[j0 * 8 + j][r] = vreg[i][j];
                }
            }
            __syncthreads();
            // prefetch next tile (wraps to tile 0 for the next pass; final wrap harmless)
            int kn = (it + 1 < nt) ? (it + 1) * 64 : 0;
#pragma unroll
            for (int i = 0; i < 4; i++) kreg[i] = *(const bf16x8*)(ksrc + (size_t)(kn + i * 16 + krow) * kstride);
#pragma unroll
            for (int i = 0; i < 2; i++) vreg[i] = *(const bf16x8*)(vb + (size_t)(kn + i * 32 + vr) * S1);

            int kb = it * 64;
#pragma unroll
            for (int sub = 0; sub < 2; sub++) {
                int kk = kb + sub * 32;
                if (kk > qw + 15) break;   // masked for this wave (no barriers inside)
                // QK^T (swapped): lane holds col=q(l15), row=k(lg*4+r)
                f32x4 st[2];
                __builtin_amdgcn_s_setprio(1);
#pragma unroll
                for (int tt = 0; tt < 2; tt++) {
                    f32x4 z = {};
#pragma unroll
                    for (int c = 0; c < 4; c++) {
                        int row = sub * 32 + tt * 16 + l15;
                        int idx = ((row << 7) + c * 32 + lg * 8) ^ ((row & 7) << 3);
                        bf16x8 kf = *(const bf16x8*)&Klds[idx];
                        z = __builtin_amdgcn_mfma_f32_16x16x32_bf16(kf, qf[c], z, 0, 0, 0);
                    }
                    st[tt] = z;
                }
                __builtin_amdgcn_s_setprio(0);
                float s[8], lm = -1e30f;
                if (kk + 31 <= qw) {   // wave-uniform: fully unmasked
#pragma unroll
                    for (int tt = 0; tt < 2; tt++)
#pragma unroll
                        for (int r = 0; r < 4; r++) {
                            float sv = st[tt][r];
                            s[tt * 4 + r] = sv;
                            lm = fmaxf(lm, sv);
                        }
                } else {
#pragma unroll
                    for (int tt = 0; tt < 2; tt++)
#pragma unroll
                        for (int r = 0; r < 4; r++) {
                            int kgl = kk + tt * 16 + lg * 4 + r;
                            float sv = st[tt][r];
                            if (kgl > qg) sv = -1e30f;
                            s[tt * 4 + r] = sv;
                            lm = fmaxf(lm, sv);
                        }
                }
                // defer-max: full rescale path only when max grew > ~8 nats (11.5 bits)
                if (__any(lm > m_run + 11.5f)) {
                    float rm = lm;
                    rm = fmaxf(rm, __shfl_xor(rm, 16));
                    rm = fmaxf(rm, __shfl_xor(rm, 32));
                    float m_new = fmaxf(m_run, rm);
                    float sc = exp2f(m_run - m_new);
                    l_part *= sc;
#pragma unroll
                    for (int r = 0; r < 4; r++) {
                        float oscr = __shfl(sc, lg * 4 + r);
#pragma unroll
                        for (int dt = 0; dt < 4; dt++) acc[dt][r] *= oscr;
                    }
                    m_run = m_new;
                }
                float pv[8];
#pragma unroll
                for (int j = 0; j < 8; j++) { pv[j] = exp2f(s[j] - m_run); l_part += pv[j]; }
                bf16x4 pk0, pk1;
#pragma unroll
                for (int r = 0; r < 4; r++) { pk0[r] = (bf16)pv[r]; pk1[r] = (bf16)pv[4 + r]; }
                *(bf16x4*)&Plds[w][l15][lg * 4] = pk0;
                *(bf16x4*)&Plds[w][l15][16 + lg * 4] = pk1;
                asm volatile("s_waitcnt lgkmcnt(0)" ::: "memory");
                __builtin_amdgcn_sched_barrier(0);
                bf16x8 paf = *(const bf16x8*)&Plds[w][l15][lg * 8];
                __builtin_amdgcn_s_setprio(1);
#pragma unroll
                for (int dt = 0; dt < 4; dt++) {
                    bf16x8 vf = *(const bf16x8*)&Vt[dt * 16 + l15][sub * 32 + lg * 8];
                    acc[dt] = __builtin_amdgcn_mfma_f32_16x16x32_bf16(paf, vf, acc[dt], 0, 0, 0);
                }
                __builtin_amdgcn_s_setprio(0);
            }
        }

        float l = l_part;
        l += __shfl_xor(l, 16);
        l += __shfl_xor(l, 32);
        float linv = 1.0f / l;   // stats live in q=l15 domain
#pragma unroll
        for (int r = 0; r < 4; r++) {
            float li = __shfl(linv, lg * 4 + r);
            size_t orow = (size_t)(b * T_SEQ + qw + lg * 4 + r);
#pragma unroll
            for (int dt = 0; dt < 4; dt++)
                O[orow * DMODEL + h * DHEAD + dt * 16 + l15] = (bf16)(acc[dt][r] * li);
        }
    }
}

// ---------------------------------------------------------------- launch
extern "C" void kernel_launch(void* const* d_in, const int* in_sizes, int n_in,
                              void* d_out, int out_size, void* d_ws, size_t ws_size,
                              hipStream_t stream) {
    const float* x = (const float*)d_in[0];
    const float* pos = (const float*)d_in[1];
    const float* Wqc = (const float*)d_in[2];  const float* bqc = (const float*)d_in[3];
    const float* Wkc = (const float*)d_in[4];  const float* bkc = (const float*)d_in[5];
    const float* Wqs = (const float*)d_in[6];  const float* bqs = (const float*)d_in[7];
    const float* Wks = (const float*)d_in[8];  const float* bks = (const float*)d_in[9];
    const float* Wv  = (const float*)d_in[10]; const float* bv  = (const float*)d_in[11];
    const float* Wo  = (const float*)d_in[12]; const float* bo  = (const float*)d_in[13];
    const float* ln1w = (const float*)d_in[14]; const float* ln1b = (const float*)d_in[15];
    const float* ln2w = (const float*)d_in[16]; const float* ln2b = (const float*)d_in[17];
    const float* Wf1 = (const float*)d_in[18]; const float* bf1 = (const float*)d_in[19];
    const float* Wf2 = (const float*)d_in[20]; const float* bf2 = (const float*)d_in[21];
    float* out = (float*)d_out;

    char* wsp = (char*)d_ws;
    size_t off = 0;
    auto alloc = [&](size_t bytes) { void* p = wsp + off; off += (bytes + 255) & ~(size_t)255; return p; };
    const size_t DD = (size_t)DMODEL * DMODEL;
    const size_t RD = (size_t)NROWS * DMODEL;
    bf16* Wcat1 = (bf16*)alloc(3 * DD * 2);     // [Qc|Kc|V] transposed
    bf16* Wcat2 = (bf16*)alloc(2 * DD * 2);     // [Qs|Ks] transposed
    bf16* WoT  = (bf16*)alloc(DD * 2);
    bf16* Wf1T = (bf16*)alloc((size_t)DMODEL * DFFN * 2);
    bf16* Wf2T = (bf16*)alloc((size_t)DMODEL * DFFN * 2);
    float* bc1 = (float*)alloc(3 * DMODEL * 4);
    float* bc2 = (float*)alloc(2 * DMODEL * 4);
    bf16* hb   = (bf16*)alloc(RD * 2);
    bf16* posb = (bf16*)alloc(RD * 2);
    bf16* C1   = (bf16*)alloc((size_t)NROWS * S1 * 2);  // [Qc|Kc|V]
    bf16* C2   = (bf16*)alloc((size_t)NROWS * S2 * 2);  // [Qs|Ks]
    bf16* Ab   = (bf16*)alloc(RD * 2);
    float* x2  = (float*)alloc(RD * 4);
    bf16* h2b  = (bf16*)alloc(RD * 2);
    bf16* gb   = (bf16*)alloc((size_t)NROWS * DFFN * 2);

    // 1) weight transposes
    TP6 tp;
    tp.src[0] = Wqc; tp.dst[0] = Wcat1;
    tp.src[1] = Wkc; tp.dst[1] = Wcat1 + DD;
    tp.src[2] = Wv;  tp.dst[2] = Wcat1 + 2 * DD;
    tp.src[3] = Wqs; tp.dst[3] = Wcat2;
    tp.src[4] = Wks; tp.dst[4] = Wcat2 + DD;
    tp.src[5] = Wo;  tp.dst[5] = WoT;
    transpose6<<<dim3(32, 32, 6), 256, 0, stream>>>(tp);
    transpose_f32_to_bf16<<<dim3(DFFN / 32, DMODEL / 32), 256, 0, stream>>>(Wf1, Wf1T, DMODEL, DFFN);
    transpose_f32_to_bf16<<<dim3(DMODEL / 32, DFFN / 32), 256, 0, stream>>>(Wf2, Wf2T, DFFN, DMODEL);
    concat_bias3<<<12, 256, 0, stream>>>(bqc, bkc, bv, bc1, 3 * DMODEL);
    concat_bias3<<<8, 256, 0, stream>>>(bqs, bks, bqs, bc2, 2 * DMODEL);

    // 2) LN1 + pos cast
    layernorm_bf16<<<NROWS, 256, 0, stream>>>(x, ln1w, ln1b, hb);
    cast_f32_bf16<<<(RD / 4 + 255) / 256, 256, 0, stream>>>(pos, posb, RD / 4);

    // 3) fused projections (Q columns prescaled by QSCALE)
    gemm_glds<128, 0, 1><<<dim3(S1 / 128, NROWS / 128), 256, 0, stream>>>(hb, Wcat1, bc1, nullptr, C1, NROWS, S1, DMODEL);
    gemm_glds<128, 0, 1><<<dim3(S2 / 128, NROWS / 128), 256, 0, stream>>>(posb, Wcat2, bc2, nullptr, C2, NROWS, S2, DMODEL);

    // 4) flash attention (work-paired blocks: j runs q-tiles {31-j, j})
    flash_attn<<<dim3(16, NBATCH * NHEAD), 256, 0, stream>>>(C1, C2, Ab);

    // 5) Wo + residual -> x2 (f32)
    gemm_glds<64, 2, 0><<<dim3(DMODEL / 64, NROWS / 128), 256, 0, stream>>>(Ab, WoT, bo, x, x2, NROWS, DMODEL, DMODEL);

    // 6) LN2
    layernorm_bf16<<<NROWS, 256, 0, stream>>>(x2, ln2w, ln2b, h2b);

    // 7) FFN1 + GELU
    gemm_glds<128, 1, 0><<<dim3(DFFN / 128, NROWS / 128), 256, 0, stream>>>(h2b, Wf1T, bf1, nullptr, gb, NROWS, DFFN, DMODEL);

    // 8) FFN2 + residual -> out (f32)
    gemm_glds<64, 2, 0><<<dim3(DMODEL / 64, NROWS / 128), 256, 0, stream>>>(gb, Wf2T, bf2, x2, out, NROWS, DMODEL, DFFN);
}